// Round 2
// baseline (570.635 us; speedup 1.0000x reference)
//
#include <hip/hip_runtime.h>
#include <hip/hip_bf16.h>
#include <hip/hip_fp16.h>

#define N_NODES 100000
#define E_EDGES 1600000
#define IN_F    256
#define HEADS   4
#define DF      32
#define HD      128           // HEADS*DF
#define NEG_SLOPE 0.2f
#define SLOTS   64            // max in-degree capacity (Poisson(16): P(>64) ~ 1e-20)

#define XCDS 8
#define NODES_PER_XCD (N_NODES / XCDS)     // 12500

#define NB_GEMM ((N_NODES + 63) / 64)      // 1563 gemm tiles
#define GRPS    ((NB_GEMM + 7) / 8)        // 196 groups of 16 blocks (8 gemm + 8 build)
#define CHUNK_E ((E_EDGES + GRPS - 1) / GRPS)   // 8164 edges per build chunk

typedef __attribute__((ext_vector_type(8))) short  short8;   // 8 bf16 raw
typedef __attribute__((ext_vector_type(8))) unsigned short ushort8;
typedef __attribute__((ext_vector_type(4))) unsigned short ushort4v;
typedef __attribute__((ext_vector_type(4))) float  f32x4;
typedef __attribute__((ext_vector_type(4))) _Float16 h16x4;

// rne fp32 -> bf16 split: v ~= hi + lo; returns (hi | lo<<16)
__device__ inline unsigned split_bf16(float v) {
    unsigned u  = __builtin_bit_cast(unsigned, v);
    unsigned hb = (u + 0x7FFFu + ((u >> 16) & 1u)) >> 16;
    float    hf = __builtin_bit_cast(float, hb << 16);
    float    l  = v - hf;
    unsigned ul = __builtin_bit_cast(unsigned, l);
    unsigned lb = (ul + 0x7FFFu + ((ul >> 16) & 1u)) >> 16;
    return (hb & 0xFFFFu) | (lb << 16);
}

// ------ 0. split+transpose weights ------
__global__ void k_prep_w(const float* __restrict__ wsrc,
                         const float* __restrict__ wdst,
                         unsigned short* __restrict__ wsT_hi,
                         unsigned short* __restrict__ wsT_lo,
                         unsigned short* __restrict__ wdT_hi,
                         unsigned short* __restrict__ wdT_lo) {
    int i = blockIdx.x * 256 + threadIdx.x;
    if (i >= IN_F * HD) return;
    int k = i >> 7, n = i & 127;
    unsigned p;
    p = split_bf16(wsrc[i]);
    wsT_hi[n * IN_F + k] = (unsigned short)(p & 0xFFFFu);
    wsT_lo[n * IN_F + k] = (unsigned short)(p >> 16);
    p = split_bf16(wdst[i]);
    wdT_hi[n * IN_F + k] = (unsigned short)(p & 0xFFFFu);
    wdT_lo[n * IN_F + k] = (unsigned short)(p >> 16);
}

// ------ 1. heterogeneous: dual GEMM tiles + bucket-build blocks in ONE launch ------
// Per 16-block group: slots 0-7 = gemm (blockIdx%8 -> XCD round-robin preserved),
// slots 8-15 = build with x = slot-8 (actual XCD = g%8 = x -> epair writes XCD-local).
// Build has no dependence on gemm; its atomic/L2 latency hides in gemm's idle issue slots.
#define BK  32
#define LDK (BK + 8)   // ushort stride 40 -> 80 B: 16B-aligned; 2-way bank alias = free

__global__ void __launch_bounds__(256)
k_gemm_build(const float* __restrict__ x,
             const unsigned short* __restrict__ wsT_hi,
             const unsigned short* __restrict__ wsT_lo,
             const unsigned short* __restrict__ wdT_hi,
             const unsigned short* __restrict__ wdT_lo,
             const float* __restrict__ bsv,
             const float* __restrict__ bdv,
             _Float16* __restrict__ el, float* __restrict__ er,
             const int* __restrict__ src, const int* __restrict__ dst,
             int* __restrict__ cnt, int2* __restrict__ epair) {
    __shared__ unsigned short xs_hi[64][LDK];
    __shared__ unsigned short xs_lo[64][LDK];
    __shared__ unsigned short ws_hi[128][LDK];
    __shared__ unsigned short ws_lo[128][LDK];
    __shared__ unsigned short wd_hi[128][LDK];
    __shared__ unsigned short wd_lo[128][LDK];   // total 51.2 KB

    int g    = blockIdx.x;
    int grp  = g >> 4, slot = g & 15;

    if (slot >= 8) {
        // ---- build role ----
        int xcd = slot - 8;
        int lo = xcd * NODES_PER_XCD;
        int hi = lo + NODES_PER_XCD;
        int e0 = grp * CHUNK_E;
        int e1 = e0 + CHUNK_E; if (e1 > E_EDGES) e1 = E_EDGES;
        for (int e = e0 + threadIdx.x; e < e1; e += 256) {
            int d = dst[e];
            if (d >= lo && d < hi) {
                int pos = atomicAdd(&cnt[d], 1);
                if (pos < SLOTS) epair[((long)d << 6) + pos] = make_int2(src[e], e);
            }
        }
        return;
    }

    // ---- gemm role ----
    int gid = grp * 8 + slot;
    if (gid >= NB_GEMM) return;

    int tid  = threadIdx.x;
    int wave = tid >> 6, lane = tid & 63;
    int quad = lane >> 4, l16 = lane & 15;
    int rhalf = wave & 1, chalf = wave >> 1;
    int row0 = gid * 64;

    f32x4 accS[2][4], accD[2][4];
#pragma unroll
    for (int a = 0; a < 2; ++a)
#pragma unroll
        for (int b = 0; b < 4; ++b) {
            accS[a][b] = (f32x4){0.f, 0.f, 0.f, 0.f};
            accD[a][b] = (f32x4){0.f, 0.f, 0.f, 0.f};
        }

    for (int kc = 0; kc < IN_F / BK; ++kc) {
        __syncthreads();
#pragma unroll
        for (int i = 0; i < 2; ++i) {
            int v = i * 256 + tid;
            int r = v >> 3, c = (v & 7) * 4;
            int gr = row0 + r;
            float4 val = make_float4(0.f, 0.f, 0.f, 0.f);
            if (gr < N_NODES)
                val = *(const float4*)(x + gr * IN_F + kc * BK + c);
            unsigned p0 = split_bf16(val.x);
            unsigned p1 = split_bf16(val.y);
            unsigned p2 = split_bf16(val.z);
            unsigned p3 = split_bf16(val.w);
            ushort4v h, l;
            h.x = (unsigned short)(p0 & 0xFFFFu); l.x = (unsigned short)(p0 >> 16);
            h.y = (unsigned short)(p1 & 0xFFFFu); l.y = (unsigned short)(p1 >> 16);
            h.z = (unsigned short)(p2 & 0xFFFFu); l.z = (unsigned short)(p2 >> 16);
            h.w = (unsigned short)(p3 & 0xFFFFu); l.w = (unsigned short)(p3 >> 16);
            *(ushort4v*)(&xs_hi[r][c]) = h;
            *(ushort4v*)(&xs_lo[r][c]) = l;
        }
#pragma unroll
        for (int i = 0; i < 2; ++i) {
            int v = i * 256 + tid;
            int n = v >> 2, c = (v & 3) * 8;
            int go = n * IN_F + kc * BK + c;
            *(ushort8*)(&ws_hi[n][c]) = *(const ushort8*)(wsT_hi + go);
            *(ushort8*)(&ws_lo[n][c]) = *(const ushort8*)(wsT_lo + go);
            *(ushort8*)(&wd_hi[n][c]) = *(const ushort8*)(wdT_hi + go);
            *(ushort8*)(&wd_lo[n][c]) = *(const ushort8*)(wdT_lo + go);
        }
        __syncthreads();

        int kb = quad * 8;
        int r0 = rhalf * 32 + l16, r1 = r0 + 16;
        short8 ah0 = *(const short8*)(&xs_hi[r0][kb]);
        short8 al0 = *(const short8*)(&xs_lo[r0][kb]);
        short8 ah1 = *(const short8*)(&xs_hi[r1][kb]);
        short8 al1 = *(const short8*)(&xs_lo[r1][kb]);
#pragma unroll
        for (int ct = 0; ct < 4; ++ct) {
            int n = chalf * 64 + ct * 16 + l16;
            short8 bsh = *(const short8*)(&ws_hi[n][kb]);
            short8 bsl = *(const short8*)(&ws_lo[n][kb]);
            short8 bdh = *(const short8*)(&wd_hi[n][kb]);
            short8 bdl = *(const short8*)(&wd_lo[n][kb]);
            accS[0][ct] = __builtin_amdgcn_mfma_f32_16x16x32_bf16(ah0, bsh, accS[0][ct], 0, 0, 0);
            accS[0][ct] = __builtin_amdgcn_mfma_f32_16x16x32_bf16(ah0, bsl, accS[0][ct], 0, 0, 0);
            accS[0][ct] = __builtin_amdgcn_mfma_f32_16x16x32_bf16(al0, bsh, accS[0][ct], 0, 0, 0);
            accS[1][ct] = __builtin_amdgcn_mfma_f32_16x16x32_bf16(ah1, bsh, accS[1][ct], 0, 0, 0);
            accS[1][ct] = __builtin_amdgcn_mfma_f32_16x16x32_bf16(ah1, bsl, accS[1][ct], 0, 0, 0);
            accS[1][ct] = __builtin_amdgcn_mfma_f32_16x16x32_bf16(al1, bsh, accS[1][ct], 0, 0, 0);
            accD[0][ct] = __builtin_amdgcn_mfma_f32_16x16x32_bf16(ah0, bdh, accD[0][ct], 0, 0, 0);
            accD[0][ct] = __builtin_amdgcn_mfma_f32_16x16x32_bf16(ah0, bdl, accD[0][ct], 0, 0, 0);
            accD[0][ct] = __builtin_amdgcn_mfma_f32_16x16x32_bf16(al0, bdh, accD[0][ct], 0, 0, 0);
            accD[1][ct] = __builtin_amdgcn_mfma_f32_16x16x32_bf16(ah1, bdh, accD[1][ct], 0, 0, 0);
            accD[1][ct] = __builtin_amdgcn_mfma_f32_16x16x32_bf16(ah1, bdl, accD[1][ct], 0, 0, 0);
            accD[1][ct] = __builtin_amdgcn_mfma_f32_16x16x32_bf16(al1, bdh, accD[1][ct], 0, 0, 0);
        }
    }

    // epilogue: C/D layout col=lane&15, row=quad*4+reg
#pragma unroll
    for (int ct = 0; ct < 4; ++ct) {
        int gc = chalf * 64 + ct * 16 + l16;
        float bsf = bsv[gc];
        float bdf = bdv[gc];
#pragma unroll
        for (int rt = 0; rt < 2; ++rt) {
            int grb = row0 + rhalf * 32 + rt * 16 + quad * 4;
#pragma unroll
            for (int r = 0; r < 4; ++r) {
                int gr = grb + r;
                if (gr < N_NODES) {
                    el[gr * HD + gc] = (_Float16)(accS[rt][ct][r] + bsf);
                    er[gr * HD + gc] = accD[rt][ct][r] + bdf;
                }
            }
        }
    }
}

// ------ 3. fused per-node softmax + aggregate ------
// 32 lanes/node, 4 nodes per 128-block. No barriers (wave-local LDS).
__global__ void __launch_bounds__(128)
k_node(const int* __restrict__ cnt,
       const int2* __restrict__ epair,
       const _Float16* __restrict__ el, const float* __restrict__ er,
       const float* __restrict__ attn,
       float* __restrict__ out0, float* __restrict__ out1) {
    __shared__ float pex[4][SLOTS][HEADS];   // 4 KB

    int nd = threadIdx.x >> 5;               // node-in-block
    int d = blockIdx.x * 4 + nd;
    int l = threadIdx.x & 31;
    int h = l >> 3;

    float4 rv = *(const float4*)(er + d * HD + l * 4);
    float4 av = *(const float4*)(attn + h * DF + (l & 7) * 4);

    int deg = cnt[d];
    deg = deg < SLOTS ? deg : SLOTS;
    const int2* row = epair + ((long)d << 6);

    int2 epA = (l      < deg) ? row[l]      : make_int2(0, 0);
    int2 epB = (32 + l < deg) ? row[32 + l] : make_int2(0, 0);

    f32x4 acc = (f32x4){0.f, 0.f, 0.f, 0.f};
    float den = 0.f;

    int s0 = __shfl(epA.x, 0, 32);
    h16x4 evhN = (deg > 0) ? *(const h16x4*)(el + (long)s0 * HD + l * 4)
                           : (h16x4){0, 0, 0, 0};

    for (int i = 0; i < deg; ++i) {
        h16x4 evh = evhN;
        if (i + 1 < deg) {
            int sn = (i + 1 < 32) ? __shfl(epA.x, i + 1, 32)
                                  : __shfl(epB.x, i + 1 - 32, 32);
            evhN = *(const h16x4*)(el + (long)sn * HD + l * 4);
        }
        f32x4 ev = __builtin_convertvector(evh, f32x4);
        float p = 0.f, tm;
        tm = ev[0] + rv.x; tm = tm > 0.f ? tm : NEG_SLOPE * tm; p += av.x * tm;
        tm = ev[1] + rv.y; tm = tm > 0.f ? tm : NEG_SLOPE * tm; p += av.y * tm;
        tm = ev[2] + rv.z; tm = tm > 0.f ? tm : NEG_SLOPE * tm; p += av.z * tm;
        tm = ev[3] + rv.w; tm = tm > 0.f ? tm : NEG_SLOPE * tm; p += av.w * tm;
        p += __shfl_xor(p, 1);
        p += __shfl_xor(p, 2);
        p += __shfl_xor(p, 4);
        float ex = __expf(p);
        den += ex;
        acc[0] += ex * ev[0]; acc[1] += ex * ev[1];
        acc[2] += ex * ev[2]; acc[3] += ex * ev[3];
        if ((l & 7) == 0) pex[nd][i][h] = ex;
    }

    float rden = den > 0.f ? 1.0f / den : 0.f;
    f32x4 fa;
    fa[0] = acc[0] * rden * 0.25f; fa[1] = acc[1] * rden * 0.25f;
    fa[2] = acc[2] * rden * 0.25f; fa[3] = acc[3] * rden * 0.25f;
    fa[0] += __shfl_xor(fa[0], 8); fa[0] += __shfl_xor(fa[0], 16);
    fa[1] += __shfl_xor(fa[1], 8); fa[1] += __shfl_xor(fa[1], 16);
    fa[2] += __shfl_xor(fa[2], 8); fa[2] += __shfl_xor(fa[2], 16);
    fa[3] += __shfl_xor(fa[3], 8); fa[3] += __shfl_xor(fa[3], 16);
    if (l < 8) *(f32x4*)(out0 + d * DF + l * 4) = fa;

    // wave-local LDS: ensure ds_writes visible to cross-lane ds_reads
    __asm__ volatile("s_waitcnt lgkmcnt(0)" ::: "memory");

    float r0 = __shfl(rden, 0, 32);
    float r1 = __shfl(rden, 8, 32);
    float r2 = __shfl(rden, 16, 32);
    float r3 = __shfl(rden, 24, 32);

    if (l < deg) {
        float4 exv = *(const float4*)(&pex[nd][l][0]);
        out1[epA.y] = 0.25f * (exv.x * r0 + exv.y * r1 + exv.z * r2 + exv.w * r3);
    }
    if (32 + l < deg) {
        float4 exv = *(const float4*)(&pex[nd][32 + l][0]);
        out1[epB.y] = 0.25f * (exv.x * r0 + exv.y * r1 + exv.z * r2 + exv.w * r3);
    }
}

extern "C" void kernel_launch(void* const* d_in, const int* in_sizes, int n_in,
                              void* d_out, int out_size, void* d_ws, size_t ws_size,
                              hipStream_t stream) {
    const float* x     = (const float*)d_in[0];
    const float* w_src = (const float*)d_in[1];
    const float* b_src = (const float*)d_in[2];
    const float* w_dst = (const float*)d_in[3];
    const float* b_dst = (const float*)d_in[4];
    const float* attn  = (const float*)d_in[5];
    const int* src = (const int*)d_in[6];
    const int* dst = (const int*)d_in[7];

    char* ws = (char*)d_ws;
    _Float16* el    = (_Float16*)(ws + 0);          // N*128 fp16 = 25.6 MB
    float*    er    = (float*)(ws + 25600000);      // 51.2 MB
    int*      cnt   = (int*)(ws + 76800000);        // 400 KB
    int2*     epair = (int2*)(ws + 77200000);       // N*64*8 = 51.2 MB
    unsigned short* wsT_hi = (unsigned short*)(ws + 128400000);  // 64 KB each
    unsigned short* wsT_lo = (unsigned short*)(ws + 128465536);
    unsigned short* wdT_hi = (unsigned short*)(ws + 128531072);
    unsigned short* wdT_lo = (unsigned short*)(ws + 128596608);

    float* out0 = (float*)d_out;                // ft.mean: N*32 fp32
    float* out1 = out0 + N_NODES * DF;          // a.mean:  E fp32

    (void)hipMemsetAsync(cnt, 0, N_NODES * sizeof(int), stream);

    k_prep_w<<<128, 256, 0, stream>>>(w_src, w_dst, wsT_hi, wsT_lo, wdT_hi, wdT_lo);
    k_gemm_build<<<GRPS * 16, 256, 0, stream>>>(x, wsT_hi, wsT_lo, wdT_hi, wdT_lo,
                                                b_src, b_dst, el, er,
                                                src, dst, cnt, epair);
    k_node<<<N_NODES / 4, 128, 0, stream>>>(cnt, epair, el, er, attn, out0, out1);
}

// Round 4
// 409.222 us; speedup vs baseline: 1.3944x; 1.3944x over previous
//
#include <hip/hip_runtime.h>
#include <hip/hip_bf16.h>
#include <hip/hip_fp16.h>

#define N_NODES 100000
#define E_EDGES 1600000
#define IN_F    256
#define HEADS   4
#define DF      32
#define HD      128           // HEADS*DF
#define NEG_SLOPE 0.2f
#define SLOTS   64            // max in-degree capacity (Poisson(16): P(>64) ~ 1e-20)

#define XCDS 8
#define NODES_PER_XCD (N_NODES / XCDS)     // 12500
#define BUILD_SLICES 800
#define CHUNK ((E_EDGES + BUILD_SLICES - 1) / BUILD_SLICES)   // 2000

typedef __attribute__((ext_vector_type(8))) _Float16 half8;
typedef __attribute__((ext_vector_type(4))) float  f32x4;
typedef __attribute__((ext_vector_type(4))) _Float16 h16x4;

// ------ 0. convert+transpose weights to fp16 ------
__global__ void k_prep_w(const float* __restrict__ wsrc,
                         const float* __restrict__ wdst,
                         _Float16* __restrict__ wsT,
                         _Float16* __restrict__ wdT) {
    int i = blockIdx.x * 256 + threadIdx.x;
    if (i >= IN_F * HD) return;
    int k = i >> 7, n = i & 127;
    wsT[n * IN_F + k] = (_Float16)wsrc[i];
    wdT[n * IN_F + k] = (_Float16)wdst[i];
}

// ------ 1. dual GEMM, fp16 single-pass, LDS 25.6 KB -> 6 blocks/CU ------
#define BK  32
#define LDK (BK + 8)   // fp16 stride 40 -> 80 B: 16B-aligned; 2-way bank alias = free

__global__ void __launch_bounds__(256)
k_gemm(const float* __restrict__ x,
       const _Float16* __restrict__ wsT,
       const _Float16* __restrict__ wdT,
       const float* __restrict__ bsv,
       const float* __restrict__ bdv,
       _Float16* __restrict__ el, float* __restrict__ er) {
    __shared__ _Float16 xs[64][LDK];    // 5.12 KB
    __shared__ _Float16 ws[128][LDK];   // 10.24 KB
    __shared__ _Float16 wd[128][LDK];   // 10.24 KB -> 25.6 KB total

    int tid  = threadIdx.x;
    int wave = tid >> 6, lane = tid & 63;
    int quad = lane >> 4, l16 = lane & 15;
    int rhalf = wave & 1, chalf = wave >> 1;
    int row0 = blockIdx.x * 64;

    f32x4 accS[2][4], accD[2][4];
#pragma unroll
    for (int a = 0; a < 2; ++a)
#pragma unroll
        for (int b = 0; b < 4; ++b) {
            accS[a][b] = (f32x4){0.f, 0.f, 0.f, 0.f};
            accD[a][b] = (f32x4){0.f, 0.f, 0.f, 0.f};
        }

    for (int kc = 0; kc < IN_F / BK; ++kc) {
        __syncthreads();
        // stage x tile: 64 rows x 32 k, fp32 -> fp16
#pragma unroll
        for (int i = 0; i < 2; ++i) {
            int v = i * 256 + tid;
            int r = v >> 3, c = (v & 7) * 4;
            int gr = row0 + r;
            float4 val = make_float4(0.f, 0.f, 0.f, 0.f);
            if (gr < N_NODES)
                val = *(const float4*)(x + gr * IN_F + kc * BK + c);
            f32x4 fv = (f32x4){val.x, val.y, val.z, val.w};
            h16x4 hv = __builtin_convertvector(fv, h16x4);
            *(h16x4*)(&xs[r][c]) = hv;
        }
        // stage weight tiles: 128 rows x 32 k each, fp16 direct 16B loads
#pragma unroll
        for (int i = 0; i < 2; ++i) {
            int v = i * 256 + tid;
            int n = v >> 2, c = (v & 3) * 8;
            int go = n * IN_F + kc * BK + c;
            *(half8*)(&ws[n][c]) = *(const half8*)(wsT + go);
            *(half8*)(&wd[n][c]) = *(const half8*)(wdT + go);
        }
        __syncthreads();

        int kb = quad * 8;
        int r0 = rhalf * 32 + l16, r1 = r0 + 16;
        half8 a0 = *(const half8*)(&xs[r0][kb]);
        half8 a1 = *(const half8*)(&xs[r1][kb]);
#pragma unroll
        for (int ct = 0; ct < 4; ++ct) {
            int n = chalf * 64 + ct * 16 + l16;
            half8 bs = *(const half8*)(&ws[n][kb]);
            half8 bd = *(const half8*)(&wd[n][kb]);
            accS[0][ct] = __builtin_amdgcn_mfma_f32_16x16x32_f16(a0, bs, accS[0][ct], 0, 0, 0);
            accS[1][ct] = __builtin_amdgcn_mfma_f32_16x16x32_f16(a1, bs, accS[1][ct], 0, 0, 0);
            accD[0][ct] = __builtin_amdgcn_mfma_f32_16x16x32_f16(a0, bd, accD[0][ct], 0, 0, 0);
            accD[1][ct] = __builtin_amdgcn_mfma_f32_16x16x32_f16(a1, bd, accD[1][ct], 0, 0, 0);
        }
    }

    // epilogue: C/D layout col=lane&15, row=quad*4+reg
#pragma unroll
    for (int ct = 0; ct < 4; ++ct) {
        int gc = chalf * 64 + ct * 16 + l16;
        float bsf = bsv[gc];
        float bdf = bdv[gc];
#pragma unroll
        for (int rt = 0; rt < 2; ++rt) {
            int grb = row0 + rhalf * 32 + rt * 16 + quad * 4;
#pragma unroll
            for (int r = 0; r < 4; ++r) {
                int gr = grb + r;
                if (gr < N_NODES) {
                    el[gr * HD + gc] = (_Float16)(accS[rt][ct][r] + bsf);
                    er[gr * HD + gc] = accD[rt][ct][r] + bdf;
                }
            }
        }
    }
}

// ------ 2. bucket build, XCD-partitioned by dst range ------
__global__ void __launch_bounds__(256)
k_build(const int* __restrict__ src, const int* __restrict__ dst,
        int* __restrict__ cnt, int2* __restrict__ epair) {
    int x = blockIdx.x & 7;
    int j = blockIdx.x >> 3;
    int lo = x * NODES_PER_XCD;
    int hi = lo + NODES_PER_XCD;
    int e0 = j * CHUNK;
    int e1 = e0 + CHUNK; if (e1 > E_EDGES) e1 = E_EDGES;
    for (int e = e0 + threadIdx.x; e < e1; e += 256) {
        int d = dst[e];
        if (d >= lo && d < hi) {
            int pos = atomicAdd(&cnt[d], 1);
            if (pos < SLOTS) epair[((long)d << 6) + pos] = make_int2(src[e], e);
        }
    }
}

// ------ 3. fused per-node softmax + aggregate, depth-3 gather prefetch ------
__global__ void __launch_bounds__(128)
k_node(const int* __restrict__ cnt,
       const int2* __restrict__ epair,
       const _Float16* __restrict__ el, const float* __restrict__ er,
       const float* __restrict__ attn,
       float* __restrict__ out0, float* __restrict__ out1) {
    __shared__ float pex[4][SLOTS][HEADS];   // 4 KB

    int nd = threadIdx.x >> 5;               // node-in-block
    int d = blockIdx.x * 4 + nd;
    int l = threadIdx.x & 31;
    int h = l >> 3;

    float4 rv = *(const float4*)(er + d * HD + l * 4);
    float4 av = *(const float4*)(attn + h * DF + (l & 7) * 4);

    int deg = cnt[d];
    deg = deg < SLOTS ? deg : SLOTS;
    const int2* row = epair + ((long)d << 6);

    int2 epA = (l      < deg) ? row[l]      : make_int2(0, 0);
    int2 epB = (32 + l < deg) ? row[32 + l] : make_int2(0, 0);

    f32x4 acc = (f32x4){0.f, 0.f, 0.f, 0.f};
    float den = 0.f;

    const h16x4 zz = (h16x4){0, 0, 0, 0};
    h16x4 pf0 = zz, pf1 = zz, pf2 = zz;
    if (deg > 0) {
        int s = __shfl(epA.x, 0, 32);
        pf0 = *(const h16x4*)(el + (long)s * HD + l * 4);
    }
    if (deg > 1) {
        int s = __shfl(epA.x, 1, 32);
        pf1 = *(const h16x4*)(el + (long)s * HD + l * 4);
    }
    if (deg > 2) {
        int s = __shfl(epA.x, 2, 32);
        pf2 = *(const h16x4*)(el + (long)s * HD + l * 4);
    }

    for (int i = 0; i < deg; ++i) {
        h16x4 evh = pf0;
        pf0 = pf1; pf1 = pf2;
        int j = i + 3;
        if (j < deg) {
            int sn = (j < 32) ? __shfl(epA.x, j, 32)
                              : __shfl(epB.x, j - 32, 32);
            pf2 = *(const h16x4*)(el + (long)sn * HD + l * 4);
        } else {
            pf2 = zz;
        }
        f32x4 ev = __builtin_convertvector(evh, f32x4);
        float p = 0.f, tm;
        tm = ev[0] + rv.x; tm = tm > 0.f ? tm : NEG_SLOPE * tm; p += av.x * tm;
        tm = ev[1] + rv.y; tm = tm > 0.f ? tm : NEG_SLOPE * tm; p += av.y * tm;
        tm = ev[2] + rv.z; tm = tm > 0.f ? tm : NEG_SLOPE * tm; p += av.z * tm;
        tm = ev[3] + rv.w; tm = tm > 0.f ? tm : NEG_SLOPE * tm; p += av.w * tm;
        p += __shfl_xor(p, 1);
        p += __shfl_xor(p, 2);
        p += __shfl_xor(p, 4);
        float ex = __expf(p);
        den += ex;
        acc[0] += ex * ev[0]; acc[1] += ex * ev[1];
        acc[2] += ex * ev[2]; acc[3] += ex * ev[3];
        if ((l & 7) == 0) pex[nd][i][h] = ex;
    }

    float rden = den > 0.f ? 1.0f / den : 0.f;
    f32x4 fa;
    fa[0] = acc[0] * rden * 0.25f; fa[1] = acc[1] * rden * 0.25f;
    fa[2] = acc[2] * rden * 0.25f; fa[3] = acc[3] * rden * 0.25f;
    fa[0] += __shfl_xor(fa[0], 8); fa[0] += __shfl_xor(fa[0], 16);
    fa[1] += __shfl_xor(fa[1], 8); fa[1] += __shfl_xor(fa[1], 16);
    fa[2] += __shfl_xor(fa[2], 8); fa[2] += __shfl_xor(fa[2], 16);
    fa[3] += __shfl_xor(fa[3], 8); fa[3] += __shfl_xor(fa[3], 16);
    if (l < 8) *(f32x4*)(out0 + d * DF + l * 4) = fa;

    // wave-local LDS: ensure ds_writes visible to cross-lane ds_reads
    __asm__ volatile("s_waitcnt lgkmcnt(0)" ::: "memory");

    float r0 = __shfl(rden, 0, 32);
    float r1 = __shfl(rden, 8, 32);
    float r2 = __shfl(rden, 16, 32);
    float r3 = __shfl(rden, 24, 32);

    if (l < deg) {
        float4 exv = *(const float4*)(&pex[nd][l][0]);
        out1[epA.y] = 0.25f * (exv.x * r0 + exv.y * r1 + exv.z * r2 + exv.w * r3);
    }
    if (32 + l < deg) {
        float4 exv = *(const float4*)(&pex[nd][32 + l][0]);
        out1[epB.y] = 0.25f * (exv.x * r0 + exv.y * r1 + exv.z * r2 + exv.w * r3);
    }
}

extern "C" void kernel_launch(void* const* d_in, const int* in_sizes, int n_in,
                              void* d_out, int out_size, void* d_ws, size_t ws_size,
                              hipStream_t stream) {
    const float* x     = (const float*)d_in[0];
    const float* w_src = (const float*)d_in[1];
    const float* b_src = (const float*)d_in[2];
    const float* w_dst = (const float*)d_in[3];
    const float* b_dst = (const float*)d_in[4];
    const float* attn  = (const float*)d_in[5];
    const int* src = (const int*)d_in[6];
    const int* dst = (const int*)d_in[7];

    char* ws = (char*)d_ws;
    _Float16* el    = (_Float16*)(ws + 0);          // N*128 fp16 = 25.6 MB
    float*    er    = (float*)(ws + 25600000);      // 51.2 MB
    int*      cnt   = (int*)(ws + 76800000);        // 400 KB
    int2*     epair = (int2*)(ws + 77200000);       // N*64*8 = 51.2 MB
    _Float16* wsT   = (_Float16*)(ws + 128400000);  // 64 KB
    _Float16* wdT   = (_Float16*)(ws + 128465536);  // 64 KB

    float* out0 = (float*)d_out;                // ft.mean: N*32 fp32
    float* out1 = out0 + N_NODES * DF;          // a.mean:  E fp32

    (void)hipMemsetAsync(cnt, 0, N_NODES * sizeof(int), stream);

    k_prep_w<<<128, 256, 0, stream>>>(w_src, w_dst, wsT, wdT);
    k_gemm<<<(N_NODES + 63) / 64, 256, 0, stream>>>(x, wsT, wdT, b_src, b_dst, el, er);
    k_build<<<XCDS * BUILD_SLICES, 256, 0, stream>>>(src, dst, cnt, epair);
    k_node<<<N_NODES / 4, 128, 0, stream>>>(cnt, epair, el, er, attn, out0, out1);
}

// Round 5
// 387.249 us; speedup vs baseline: 1.4736x; 1.0567x over previous
//
#include <hip/hip_runtime.h>
#include <hip/hip_bf16.h>
#include <hip/hip_fp16.h>

#define N_NODES 100000
#define E_EDGES 1600000
#define IN_F    256
#define HEADS   4
#define DF      32
#define HD      128           // HEADS*DF
#define NEG_SLOPE 0.2f
#define SLOTS   64            // max in-degree capacity (Poisson(16): P(>64) ~ 1e-20)

#define XCDS 8
#define NODES_PER_XCD (N_NODES / XCDS)     // 12500
#define BUILD_SLICES 800
#define CHUNK ((E_EDGES + BUILD_SLICES - 1) / BUILD_SLICES)   // 2000

typedef __attribute__((ext_vector_type(8))) _Float16 half8;
typedef __attribute__((ext_vector_type(2))) _Float16 h16x2;
typedef __attribute__((ext_vector_type(4))) float  f32x4;
typedef __attribute__((ext_vector_type(4))) _Float16 h16x4;

// ------ 0. convert+transpose weights to fp16 ------
__global__ void k_prep_w(const float* __restrict__ wsrc,
                         const float* __restrict__ wdst,
                         _Float16* __restrict__ wsT,
                         _Float16* __restrict__ wdT) {
    int i = blockIdx.x * 256 + threadIdx.x;
    if (i >= IN_F * HD) return;
    int k = i >> 7, n = i & 127;
    wsT[n * IN_F + k] = (_Float16)wsrc[i];
    wdT[n * IN_F + k] = (_Float16)wdst[i];
}

// ------ 1. dual GEMM, fp16 single-pass, LDS 25.6 KB; er now stored fp16 ------
#define BK  32
#define LDK (BK + 8)   // fp16 stride 40 -> 80 B: 16B-aligned; 2-way bank alias = free

__global__ void __launch_bounds__(256)
k_gemm(const float* __restrict__ x,
       const _Float16* __restrict__ wsT,
       const _Float16* __restrict__ wdT,
       const float* __restrict__ bsv,
       const float* __restrict__ bdv,
       _Float16* __restrict__ el, _Float16* __restrict__ er) {
    __shared__ _Float16 xs[64][LDK];    // 5.12 KB
    __shared__ _Float16 ws[128][LDK];   // 10.24 KB
    __shared__ _Float16 wd[128][LDK];   // 10.24 KB -> 25.6 KB total

    int tid  = threadIdx.x;
    int wave = tid >> 6, lane = tid & 63;
    int quad = lane >> 4, l16 = lane & 15;
    int rhalf = wave & 1, chalf = wave >> 1;
    int row0 = blockIdx.x * 64;

    f32x4 accS[2][4], accD[2][4];
#pragma unroll
    for (int a = 0; a < 2; ++a)
#pragma unroll
        for (int b = 0; b < 4; ++b) {
            accS[a][b] = (f32x4){0.f, 0.f, 0.f, 0.f};
            accD[a][b] = (f32x4){0.f, 0.f, 0.f, 0.f};
        }

    for (int kc = 0; kc < IN_F / BK; ++kc) {
        __syncthreads();
        // stage x tile: 64 rows x 32 k, fp32 -> fp16
#pragma unroll
        for (int i = 0; i < 2; ++i) {
            int v = i * 256 + tid;
            int r = v >> 3, c = (v & 7) * 4;
            int gr = row0 + r;
            float4 val = make_float4(0.f, 0.f, 0.f, 0.f);
            if (gr < N_NODES)
                val = *(const float4*)(x + gr * IN_F + kc * BK + c);
            f32x4 fv = (f32x4){val.x, val.y, val.z, val.w};
            h16x4 hv = __builtin_convertvector(fv, h16x4);
            *(h16x4*)(&xs[r][c]) = hv;
        }
        // stage weight tiles: 128 rows x 32 k each, fp16 direct 16B loads
#pragma unroll
        for (int i = 0; i < 2; ++i) {
            int v = i * 256 + tid;
            int n = v >> 2, c = (v & 3) * 8;
            int go = n * IN_F + kc * BK + c;
            *(half8*)(&ws[n][c]) = *(const half8*)(wsT + go);
            *(half8*)(&wd[n][c]) = *(const half8*)(wdT + go);
        }
        __syncthreads();

        int kb = quad * 8;
        int r0 = rhalf * 32 + l16, r1 = r0 + 16;
        half8 a0 = *(const half8*)(&xs[r0][kb]);
        half8 a1 = *(const half8*)(&xs[r1][kb]);
#pragma unroll
        for (int ct = 0; ct < 4; ++ct) {
            int n = chalf * 64 + ct * 16 + l16;
            half8 bs = *(const half8*)(&ws[n][kb]);
            half8 bd = *(const half8*)(&wd[n][kb]);
            accS[0][ct] = __builtin_amdgcn_mfma_f32_16x16x32_f16(a0, bs, accS[0][ct], 0, 0, 0);
            accS[1][ct] = __builtin_amdgcn_mfma_f32_16x16x32_f16(a1, bs, accS[1][ct], 0, 0, 0);
            accD[0][ct] = __builtin_amdgcn_mfma_f32_16x16x32_f16(a0, bd, accD[0][ct], 0, 0, 0);
            accD[1][ct] = __builtin_amdgcn_mfma_f32_16x16x32_f16(a1, bd, accD[1][ct], 0, 0, 0);
        }
    }

    // epilogue: C/D layout col=lane&15, row=quad*4+reg
#pragma unroll
    for (int ct = 0; ct < 4; ++ct) {
        int gc = chalf * 64 + ct * 16 + l16;
        float bsf = bsv[gc];
        float bdf = bdv[gc];
#pragma unroll
        for (int rt = 0; rt < 2; ++rt) {
            int grb = row0 + rhalf * 32 + rt * 16 + quad * 4;
#pragma unroll
            for (int r = 0; r < 4; ++r) {
                int gr = grb + r;
                if (gr < N_NODES) {
                    el[gr * HD + gc] = (_Float16)(accS[rt][ct][r] + bsf);
                    er[gr * HD + gc] = (_Float16)(accD[rt][ct][r] + bdf);
                }
            }
        }
    }
}

// ------ 2. bucket build, XCD-partitioned by dst range ------
__global__ void __launch_bounds__(256)
k_build(const int* __restrict__ src, const int* __restrict__ dst,
        int* __restrict__ cnt, int2* __restrict__ epair) {
    int x = blockIdx.x & 7;
    int j = blockIdx.x >> 3;
    int lo = x * NODES_PER_XCD;
    int hi = lo + NODES_PER_XCD;
    int e0 = j * CHUNK;
    int e1 = e0 + CHUNK; if (e1 > E_EDGES) e1 = E_EDGES;
    for (int e = e0 + threadIdx.x; e < e1; e += 256) {
        int d = dst[e];
        if (d >= lo && d < hi) {
            int pos = atomicAdd(&cnt[d], 1);
            if (pos < SLOTS) epair[((long)d << 6) + pos] = make_int2(src[e], e);
        }
    }
}

// ------ 3. fused per-node softmax + aggregate ------
// NEW layout: 4 edges/iteration x 8 lanes/edge (16 features per lane).
// Score add+leakyrelu in packed fp16; dot + aggregate accumulate in f32 (fma_mix).
// 1 reduce shuffle per 4 edges (xor 1 within the 8-lane dot), 8-edge prefetch.
__global__ void __launch_bounds__(128)
k_node(const int* __restrict__ cnt,
       const int2* __restrict__ epair,
       const _Float16* __restrict__ el, const _Float16* __restrict__ er,
       const float* __restrict__ attn,
       float* __restrict__ out0, float* __restrict__ out1) {
    __shared__ float pex[4][SLOTS][HEADS];   // 4 KB

    int nd = threadIdx.x >> 5;               // node-in-block
    int d  = blockIdx.x * 4 + nd;
    int l  = threadIdx.x & 31;
    int g  = l >> 3;                         // edge slot within iteration (0-3)
    int r  = l & 7;                          // lane within edge (8 lanes x 16 feats)
    int hh = r >> 1;                         // head
    int qq = r & 1;                          // half of head (feature group of 16)

    // node-constant: er row (fp16), features r*16..+16
    const half8* erp = (const half8*)(er + (long)d * HD + r * 16);
    half8 rv0 = erp[0], rv1 = erp[1];
    // attn (f32, full precision)
    float av[16];
#pragma unroll
    for (int k = 0; k < 16; ++k)
        av[k] = attn[hh * DF + qq * 16 + k];

    int deg = cnt[d];
    deg = deg < SLOTS ? deg : SLOTS;
    const int2* rowp = epair + ((long)d << 6);

    int2 epA = (l      < deg) ? rowp[l]      : make_int2(0, 0);
    int2 epB = (32 + l < deg) ? rowp[32 + l] : make_int2(0, 0);

    float acc[16];
#pragma unroll
    for (int k = 0; k < 16; ++k) acc[k] = 0.f;
    float den = 0.f;

    int nit = (deg + 3) >> 2;

    // prefetch iterations 0 and 1 (slots g and 4+g, both < 32 -> epA)
    half8 pf0a, pf0b, pf1a, pf1b;
    {
        int s0 = __shfl(epA.x, g, 32);
        const half8* p0 = (const half8*)(el + (long)s0 * HD + r * 16);
        pf0a = p0[0]; pf0b = p0[1];
        int s1 = __shfl(epA.x, 4 + g, 32);
        const half8* p1 = (const half8*)(el + (long)s1 * HD + r * 16);
        pf1a = p1[0]; pf1b = p1[1];
    }

    const h16x2 hz = (h16x2){(_Float16)0.f, (_Float16)0.f};
    const _Float16 hs = (_Float16)NEG_SLOPE;

    for (int b = 0; b < nit * 4; b += 4) {
        half8 ev0 = pf0a, ev1 = pf0b;
        pf0a = pf1a; pf0b = pf1b;
        // prefetch iteration b+8
        int nb = b + 8;
        int jj = nb + g; jj = jj < 63 ? jj : 63;
        int sN = (nb < 32) ? __shfl(epA.x, jj, 32) : __shfl(epB.x, jj - 32, 32);
        const half8* pn = (const half8*)(el + (long)sN * HD + r * 16);
        pf1a = pn[0]; pf1b = pn[1];

        int j = b + g;
        // score: packed fp16 add+leakyrelu, f32 dot (fma_mix)
        float p = 0.f;
#pragma unroll
        for (int k = 0; k < 8; ++k) {
            half8 eq = (k < 4) ? ev0 : ev1;
            half8 rq = (k < 4) ? rv0 : rv1;
            int e0 = (k & 3) * 2;
            h16x2 e2 = (h16x2){ eq[e0], eq[e0 + 1] };
            h16x2 r2 = (h16x2){ rq[e0], rq[e0 + 1] };
            h16x2 t   = e2 + r2;
            h16x2 pos = __builtin_elementwise_max(t, hz);
            h16x2 neg = __builtin_elementwise_min(t, hz);
            h16x2 lr  = pos + neg * hs;
            p = fmaf((float)lr[0], av[2 * k],     p);
            p = fmaf((float)lr[1], av[2 * k + 1], p);
        }
        p += __shfl_xor(p, 1, 32);           // q-pair reduce -> full head dot
        bool valid = j < deg;
        float ex = valid ? __expf(p) : 0.f;
        den += ex;
#pragma unroll
        for (int k = 0; k < 16; ++k) {
            _Float16 e = (k < 8) ? ev0[k & 7] : ev1[k & 7];
            acc[k] = fmaf(ex, (float)e, acc[k]);
        }
        if (((l & 1) == 0) && valid) pex[nd][j][hh] = ex;
    }

    // den: reduce over the 4 edge subgroups (g bits = lane bits 3,4)
    den += __shfl_xor(den, 8, 32);
    den += __shfl_xor(den, 16, 32);
    float rden = den > 0.f ? 1.0f / den : 0.f;

    // scale by this head's rden, then reduce over h (xor 2,4) and g (xor 8,16)
    float w = rden * 0.25f;
#pragma unroll
    for (int k = 0; k < 16; ++k) {
        float fa = acc[k] * w;
        fa += __shfl_xor(fa, 2, 32);
        fa += __shfl_xor(fa, 4, 32);
        fa += __shfl_xor(fa, 8, 32);
        fa += __shfl_xor(fa, 16, 32);
        acc[k] = fa;
    }
    if (l < 2) {   // lane 0: feats 0-15, lane 1: feats 16-31
        float* o = out0 + (long)d * DF + l * 16;
#pragma unroll
        for (int k = 0; k < 4; ++k) {
            *(float4*)(o + k * 4) = make_float4(acc[k * 4], acc[k * 4 + 1],
                                                acc[k * 4 + 2], acc[k * 4 + 3]);
        }
    }

    // wave-local LDS: ensure ds_writes visible to cross-lane ds_reads
    __asm__ volatile("s_waitcnt lgkmcnt(0)" ::: "memory");

    // rden per head lives on lanes r = 2h (q==0): lanes 0,2,4,6
    float r0 = __shfl(rden, 0, 32);
    float r1 = __shfl(rden, 2, 32);
    float r2 = __shfl(rden, 4, 32);
    float r3 = __shfl(rden, 6, 32);

    if (l < deg) {
        float4 exv = *(const float4*)(&pex[nd][l][0]);
        out1[epA.y] = 0.25f * (exv.x * r0 + exv.y * r1 + exv.z * r2 + exv.w * r3);
    }
    if (32 + l < deg) {
        float4 exv = *(const float4*)(&pex[nd][32 + l][0]);
        out1[epB.y] = 0.25f * (exv.x * r0 + exv.y * r1 + exv.z * r2 + exv.w * r3);
    }
}

extern "C" void kernel_launch(void* const* d_in, const int* in_sizes, int n_in,
                              void* d_out, int out_size, void* d_ws, size_t ws_size,
                              hipStream_t stream) {
    const float* x     = (const float*)d_in[0];
    const float* w_src = (const float*)d_in[1];
    const float* b_src = (const float*)d_in[2];
    const float* w_dst = (const float*)d_in[3];
    const float* b_dst = (const float*)d_in[4];
    const float* attn  = (const float*)d_in[5];
    const int* src = (const int*)d_in[6];
    const int* dst = (const int*)d_in[7];

    char* ws = (char*)d_ws;
    _Float16* el    = (_Float16*)(ws + 0);          // N*128 fp16 = 25.6 MB
    _Float16* er    = (_Float16*)(ws + 25600000);   // N*128 fp16 = 25.6 MB
    int*      cnt   = (int*)(ws + 51200000);        // 400 KB
    int2*     epair = (int2*)(ws + 51600000);       // N*64*8 = 51.2 MB
    _Float16* wsT   = (_Float16*)(ws + 102800000);  // 64 KB
    _Float16* wdT   = (_Float16*)(ws + 102865536);  // 64 KB

    float* out0 = (float*)d_out;                // ft.mean: N*32 fp32
    float* out1 = out0 + N_NODES * DF;          // a.mean:  E fp32

    (void)hipMemsetAsync(cnt, 0, N_NODES * sizeof(int), stream);

    k_prep_w<<<128, 256, 0, stream>>>(w_src, w_dst, wsT, wdT);
    k_gemm<<<(N_NODES + 63) / 64, 256, 0, stream>>>(x, wsT, wdT, b_src, b_dst, el, er);
    k_build<<<XCDS * BUILD_SLICES, 256, 0, stream>>>(src, dst, cnt, epair);
    k_node<<<N_NODES / 4, 128, 0, stream>>>(cnt, epair, el, er, attn, out0, out1);
}

// Round 6
// 364.830 us; speedup vs baseline: 1.5641x; 1.0615x over previous
//
#include <hip/hip_runtime.h>
#include <hip/hip_bf16.h>
#include <hip/hip_fp16.h>

#define N_NODES 100000
#define E_EDGES 1600000
#define IN_F    256
#define HEADS   4
#define DF      32
#define HD      128           // HEADS*DF
#define NEG_SLOPE 0.2f
#define SLOTS   64            // max in-degree capacity (Poisson(16): P(>64) ~ 1e-20)

#define XCDS 8
#define NODES_PER_XCD (N_NODES / XCDS)     // 12500
#define BUILD_SLICES 800
#define CHUNK ((E_EDGES + BUILD_SLICES - 1) / BUILD_SLICES)   // 2000

typedef __attribute__((ext_vector_type(8))) _Float16 half8;
typedef __attribute__((ext_vector_type(2))) _Float16 h16x2;
typedef __attribute__((ext_vector_type(4))) float  f32x4;
typedef __attribute__((ext_vector_type(4))) _Float16 h16x4;

// ------ 0. convert+transpose weights to fp16 ------
__global__ void k_prep_w(const float* __restrict__ wsrc,
                         const float* __restrict__ wdst,
                         _Float16* __restrict__ wsT,
                         _Float16* __restrict__ wdT) {
    int i = blockIdx.x * 256 + threadIdx.x;
    if (i >= IN_F * HD) return;
    int k = i >> 7, n = i & 127;
    wsT[n * IN_F + k] = (_Float16)wsrc[i];
    wdT[n * IN_F + k] = (_Float16)wdst[i];
}

// ------ 1. dual GEMM, fp16, reg-staged K-pipeline + coalesced LDS epilogue ------
#define BK  32
#define LDK (BK + 8)   // fp16 stride 40 -> 80 B: 16B-aligned; 2-way bank alias = free
#define STG_LD (HD + 8)  // epilogue staging stride 136 fp16 = 272B -> bank-shift 4/row

__global__ void __launch_bounds__(256)
k_gemm(const float* __restrict__ x,
       const _Float16* __restrict__ wsT,
       const _Float16* __restrict__ wdT,
       const float* __restrict__ bsv,
       const float* __restrict__ bdv,
       _Float16* __restrict__ el, _Float16* __restrict__ er) {
    __shared__ _Float16 lds[12800];   // 25.6 KB, carved below; reused by epilogue
    _Float16 (*xs)[LDK] = (_Float16 (*)[LDK])(lds);                       // 64 rows
    _Float16 (*ws)[LDK] = (_Float16 (*)[LDK])(lds + 64 * LDK);            // 128 rows
    _Float16 (*wd)[LDK] = (_Float16 (*)[LDK])(lds + 64 * LDK + 128 * LDK);

    int tid  = threadIdx.x;
    int wave = tid >> 6, lane = tid & 63;
    int quad = lane >> 4, l16 = lane & 15;
    int rhalf = wave & 1, chalf = wave >> 1;
    int row0 = blockIdx.x * 64;

    // staging coordinates (fixed per thread)
    int xr0 = tid >> 3,        xc0 = (tid & 7) * 4;   // x rows tid>>3 and +32
    int wn0 = tid >> 2,        wc0 = (tid & 3) * 8;   // w rows tid>>2 and +64

    f32x4 accS[2][4], accD[2][4];
#pragma unroll
    for (int a = 0; a < 2; ++a)
#pragma unroll
        for (int b = 0; b < 4; ++b) {
            accS[a][b] = (f32x4){0.f, 0.f, 0.f, 0.f};
            accD[a][b] = (f32x4){0.f, 0.f, 0.f, 0.f};
        }

    float4 xv[2];
    half8  wsv[2], wdv[2];

    // prologue: load kc=0 into regs
#pragma unroll
    for (int i = 0; i < 2; ++i) {
        int gr = row0 + xr0 + i * 32;
        xv[i] = (gr < N_NODES) ? *(const float4*)(x + (long)gr * IN_F + xc0)
                               : make_float4(0.f, 0.f, 0.f, 0.f);
        int go = (wn0 + i * 64) * IN_F + wc0;
        wsv[i] = *(const half8*)(wsT + go);
        wdv[i] = *(const half8*)(wdT + go);
    }
    // write kc=0 to LDS
#pragma unroll
    for (int i = 0; i < 2; ++i) {
        f32x4 fv = (f32x4){xv[i].x, xv[i].y, xv[i].z, xv[i].w};
        *(h16x4*)(&xs[xr0 + i * 32][xc0]) = __builtin_convertvector(fv, h16x4);
        *(half8*)(&ws[wn0 + i * 64][wc0]) = wsv[i];
        *(half8*)(&wd[wn0 + i * 64][wc0]) = wdv[i];
    }

    for (int kc = 0; kc < IN_F / BK; ++kc) {
        __syncthreads();                       // LDS for kc ready
        if (kc < IN_F / BK - 1) {              // issue loads for kc+1 (hide under MFMA)
            int ko = (kc + 1) * BK;
#pragma unroll
            for (int i = 0; i < 2; ++i) {
                int gr = row0 + xr0 + i * 32;
                xv[i] = (gr < N_NODES) ? *(const float4*)(x + (long)gr * IN_F + ko + xc0)
                                       : make_float4(0.f, 0.f, 0.f, 0.f);
                int go = (wn0 + i * 64) * IN_F + ko + wc0;
                wsv[i] = *(const half8*)(wsT + go);
                wdv[i] = *(const half8*)(wdT + go);
            }
        }

        int kb = quad * 8;
        int r0 = rhalf * 32 + l16, r1 = r0 + 16;
        half8 a0 = *(const half8*)(&xs[r0][kb]);
        half8 a1 = *(const half8*)(&xs[r1][kb]);
#pragma unroll
        for (int ct = 0; ct < 4; ++ct) {
            int n = chalf * 64 + ct * 16 + l16;
            half8 bs = *(const half8*)(&ws[n][kb]);
            half8 bd = *(const half8*)(&wd[n][kb]);
            accS[0][ct] = __builtin_amdgcn_mfma_f32_16x16x32_f16(a0, bs, accS[0][ct], 0, 0, 0);
            accS[1][ct] = __builtin_amdgcn_mfma_f32_16x16x32_f16(a1, bs, accS[1][ct], 0, 0, 0);
            accD[0][ct] = __builtin_amdgcn_mfma_f32_16x16x32_f16(a0, bd, accD[0][ct], 0, 0, 0);
            accD[1][ct] = __builtin_amdgcn_mfma_f32_16x16x32_f16(a1, bd, accD[1][ct], 0, 0, 0);
        }
        __syncthreads();                       // all reads of kc done
        if (kc < IN_F / BK - 1) {              // write kc+1 into (single-buffered) LDS
#pragma unroll
            for (int i = 0; i < 2; ++i) {
                f32x4 fv = (f32x4){xv[i].x, xv[i].y, xv[i].z, xv[i].w};
                *(h16x4*)(&xs[xr0 + i * 32][xc0]) = __builtin_convertvector(fv, h16x4);
                *(half8*)(&ws[wn0 + i * 64][wc0]) = wsv[i];
                *(half8*)(&wd[wn0 + i * 64][wc0]) = wdv[i];
            }
        }
    }

    // ---- epilogue: stage C tiles in LDS, store full 256B rows coalesced ----
    _Float16 (*stg)[STG_LD] = (_Float16 (*)[STG_LD])lds;   // 64 x 136 fp16 = 17.4 KB
    int orow = tid >> 2, ocol = (tid & 3) * 32;            // readback coords
    int ogr  = row0 + orow;

    // el
#pragma unroll
    for (int ct = 0; ct < 4; ++ct) {
        int gc = chalf * 64 + ct * 16 + l16;
        float bsf = bsv[gc];
#pragma unroll
        for (int rt = 0; rt < 2; ++rt) {
            int rr = rhalf * 32 + rt * 16 + quad * 4;
#pragma unroll
            for (int r = 0; r < 4; ++r)
                stg[rr + r][gc] = (_Float16)(accS[rt][ct][r] + bsf);
        }
    }
    __syncthreads();
    if (ogr < N_NODES) {
#pragma unroll
        for (int k = 0; k < 4; ++k)
            *(half8*)(el + (long)ogr * HD + ocol + k * 8) =
                *(const half8*)(&stg[orow][ocol + k * 8]);
    }
    __syncthreads();
    // er
#pragma unroll
    for (int ct = 0; ct < 4; ++ct) {
        int gc = chalf * 64 + ct * 16 + l16;
        float bdf = bdv[gc];
#pragma unroll
        for (int rt = 0; rt < 2; ++rt) {
            int rr = rhalf * 32 + rt * 16 + quad * 4;
#pragma unroll
            for (int r = 0; r < 4; ++r)
                stg[rr + r][gc] = (_Float16)(accD[rt][ct][r] + bdf);
        }
    }
    __syncthreads();
    if (ogr < N_NODES) {
#pragma unroll
        for (int k = 0; k < 4; ++k)
            *(half8*)(er + (long)ogr * HD + ocol + k * 8) =
                *(const half8*)(&stg[orow][ocol + k * 8]);
    }
}

// ------ 2. bucket build, XCD-partitioned by dst range ------
__global__ void __launch_bounds__(256)
k_build(const int* __restrict__ src, const int* __restrict__ dst,
        int* __restrict__ cnt, int2* __restrict__ epair) {
    int x = blockIdx.x & 7;
    int j = blockIdx.x >> 3;
    int lo = x * NODES_PER_XCD;
    int hi = lo + NODES_PER_XCD;
    int e0 = j * CHUNK;
    int e1 = e0 + CHUNK; if (e1 > E_EDGES) e1 = E_EDGES;
    for (int e = e0 + threadIdx.x; e < e1; e += 256) {
        int d = dst[e];
        if (d >= lo && d < hi) {
            int pos = atomicAdd(&cnt[d], 1);
            if (pos < SLOTS) epair[((long)d << 6) + pos] = make_int2(src[e], e);
        }
    }
}

// ------ 3. fused per-node softmax + aggregate ------
// 4 edges/iteration x 8 lanes/edge (16 features per lane); 8 nodes per 256-block.
// Score: packed fp16 add+leakyrelu + v_dot2_f32_f16; f32 accumulation.
__global__ void __launch_bounds__(256)
k_node(const int* __restrict__ cnt,
       const int2* __restrict__ epair,
       const _Float16* __restrict__ el, const _Float16* __restrict__ er,
       const float* __restrict__ attn,
       float* __restrict__ out0, float* __restrict__ out1) {
    __shared__ float pex[8][SLOTS][HEADS];   // 8 KB

    int nd = threadIdx.x >> 5;               // node-in-block (0-7)
    int d  = blockIdx.x * 8 + nd;
    int l  = threadIdx.x & 31;
    int g  = l >> 3;                         // edge slot within iteration (0-3)
    int r  = l & 7;                          // lane within edge (8 lanes x 16 feats)
    int hh = r >> 1;                         // head
    int qq = r & 1;                          // half of head (feature group of 16)

    // node-constant: er row (fp16), features r*16..+16
    const half8* erp = (const half8*)(er + (long)d * HD + r * 16);
    half8 rv0 = erp[0], rv1 = erp[1];
    // attn as fp16 pairs for dot2
    h16x2 av2[8];
#pragma unroll
    for (int k = 0; k < 8; ++k) {
        av2[k][0] = (_Float16)attn[hh * DF + qq * 16 + 2 * k];
        av2[k][1] = (_Float16)attn[hh * DF + qq * 16 + 2 * k + 1];
    }

    int deg = cnt[d];
    deg = deg < SLOTS ? deg : SLOTS;
    const int2* rowp = epair + ((long)d << 6);

    int2 epA = (l      < deg) ? rowp[l]      : make_int2(0, 0);
    int2 epB = (32 + l < deg) ? rowp[32 + l] : make_int2(0, 0);

    float acc[16];
#pragma unroll
    for (int k = 0; k < 16; ++k) acc[k] = 0.f;
    float den = 0.f;

    int nit = (deg + 3) >> 2;

    // prefetch iterations 0 and 1 (slots g and 4+g, both < 32 -> epA)
    half8 pf0a, pf0b, pf1a, pf1b;
    {
        int s0 = __shfl(epA.x, g, 32);
        const half8* p0 = (const half8*)(el + (long)s0 * HD + r * 16);
        pf0a = p0[0]; pf0b = p0[1];
        int s1 = __shfl(epA.x, 4 + g, 32);
        const half8* p1 = (const half8*)(el + (long)s1 * HD + r * 16);
        pf1a = p1[0]; pf1b = p1[1];
    }

    const h16x2 hz = (h16x2){(_Float16)0.f, (_Float16)0.f};
    const _Float16 hs = (_Float16)NEG_SLOPE;

    for (int b = 0; b < nit * 4; b += 4) {
        half8 ev0 = pf0a, ev1 = pf0b;
        pf0a = pf1a; pf0b = pf1b;
        // prefetch iteration b+8
        int nb = b + 8;
        int jj = nb + g; jj = jj < 63 ? jj : 63;
        int sN = (nb < 32) ? __shfl(epA.x, jj, 32) : __shfl(epB.x, jj - 32, 32);
        const half8* pn = (const half8*)(el + (long)sN * HD + r * 16);
        pf1a = pn[0]; pf1b = pn[1];

        int j = b + g;
        // score: packed fp16 add+leakyrelu, dot2 accumulate into f32
        float p = 0.f;
#pragma unroll
        for (int k = 0; k < 8; ++k) {
            half8 eq = (k < 4) ? ev0 : ev1;
            half8 rq = (k < 4) ? rv0 : rv1;
            int e0 = (k & 3) * 2;
            h16x2 t   = (h16x2){ (_Float16)(eq[e0] + rq[e0]),
                                 (_Float16)(eq[e0 + 1] + rq[e0 + 1]) };
            h16x2 pos = __builtin_elementwise_max(t, hz);
            h16x2 neg = __builtin_elementwise_min(t, hz);
            h16x2 lr  = pos + neg * hs;
            p = __builtin_amdgcn_fdot2(lr, av2[k], p, false);
        }
        p += __shfl_xor(p, 1, 32);           // q-pair reduce -> full head dot
        bool valid = j < deg;
        float ex = valid ? __expf(p) : 0.f;
        den += ex;
#pragma unroll
        for (int k = 0; k < 16; ++k) {
            _Float16 e = (k < 8) ? ev0[k & 7] : ev1[k & 7];
            acc[k] = fmaf(ex, (float)e, acc[k]);
        }
        if (((l & 1) == 0) && valid) pex[nd][j][hh] = ex;
    }

    // den: reduce over the 4 edge subgroups (g bits = lane bits 3,4)
    den += __shfl_xor(den, 8, 32);
    den += __shfl_xor(den, 16, 32);
    float rden = den > 0.f ? 1.0f / den : 0.f;

    // scale by this head's rden, then reduce over h (xor 2,4) and g (xor 8,16)
    float w = rden * 0.25f;
#pragma unroll
    for (int k = 0; k < 16; ++k) {
        float fa = acc[k] * w;
        fa += __shfl_xor(fa, 2, 32);
        fa += __shfl_xor(fa, 4, 32);
        fa += __shfl_xor(fa, 8, 32);
        fa += __shfl_xor(fa, 16, 32);
        acc[k] = fa;
    }
    if (l < 2) {   // lane 0: feats 0-15, lane 1: feats 16-31
        float* o = out0 + (long)d * DF + l * 16;
#pragma unroll
        for (int k = 0; k < 4; ++k) {
            *(float4*)(o + k * 4) = make_float4(acc[k * 4], acc[k * 4 + 1],
                                                acc[k * 4 + 2], acc[k * 4 + 3]);
        }
    }

    // wave-local LDS: ensure ds_writes visible to cross-lane ds_reads
    __asm__ volatile("s_waitcnt lgkmcnt(0)" ::: "memory");

    // rden per head lives on lanes r = 2h (q==0): lanes 0,2,4,6
    float r0 = __shfl(rden, 0, 32);
    float r1 = __shfl(rden, 2, 32);
    float r2 = __shfl(rden, 4, 32);
    float r3 = __shfl(rden, 6, 32);

    if (l < deg) {
        float4 exv = *(const float4*)(&pex[nd][l][0]);
        out1[epA.y] = 0.25f * (exv.x * r0 + exv.y * r1 + exv.z * r2 + exv.w * r3);
    }
    if (32 + l < deg) {
        float4 exv = *(const float4*)(&pex[nd][32 + l][0]);
        out1[epB.y] = 0.25f * (exv.x * r0 + exv.y * r1 + exv.z * r2 + exv.w * r3);
    }
}

extern "C" void kernel_launch(void* const* d_in, const int* in_sizes, int n_in,
                              void* d_out, int out_size, void* d_ws, size_t ws_size,
                              hipStream_t stream) {
    const float* x     = (const float*)d_in[0];
    const float* w_src = (const float*)d_in[1];
    const float* b_src = (const float*)d_in[2];
    const float* w_dst = (const float*)d_in[3];
    const float* b_dst = (const float*)d_in[4];
    const float* attn  = (const float*)d_in[5];
    const int* src = (const int*)d_in[6];
    const int* dst = (const int*)d_in[7];

    char* ws = (char*)d_ws;
    _Float16* el    = (_Float16*)(ws + 0);          // N*128 fp16 = 25.6 MB
    _Float16* er    = (_Float16*)(ws + 25600000);   // N*128 fp16 = 25.6 MB
    int*      cnt   = (int*)(ws + 51200000);        // 400 KB
    int2*     epair = (int2*)(ws + 51600000);       // N*64*8 = 51.2 MB
    _Float16* wsT   = (_Float16*)(ws + 102800000);  // 64 KB
    _Float16* wdT   = (_Float16*)(ws + 102865536);  // 64 KB

    float* out0 = (float*)d_out;                // ft.mean: N*32 fp32
    float* out1 = out0 + N_NODES * DF;          // a.mean:  E fp32

    (void)hipMemsetAsync(cnt, 0, N_NODES * sizeof(int), stream);

    k_prep_w<<<128, 256, 0, stream>>>(w_src, w_dst, wsT, wdT);
    k_gemm<<<(N_NODES + 63) / 64, 256, 0, stream>>>(x, wsT, wdT, b_src, b_dst, el, er);
    k_build<<<XCDS * BUILD_SLICES, 256, 0, stream>>>(src, dst, cnt, epair);
    k_node<<<N_NODES / 8, 256, 0, stream>>>(cnt, epair, el, er, attn, out0, out1);
}